// Round 2
// baseline (74.219 us; speedup 1.0000x reference)
//
#include <hip/hip_runtime.h>
#include <stdint.h>

// Problem constants (from reference)
#define BATCH 1024
#define FEAT  784
#define OUTF  1024
#define OR_T  32
#define AND_T 16
#define NIDX  1569          // 1 + 2*FEAT boolean input columns
#define BSTRIDE 1600        // padded uint64 words per batch-group column
#define NGROUP  16          // BATCH / 64

typedef unsigned long long u64;

// ---------------------------------------------------------------------------
// Kernel 1: build bit-packed x_in columns.
// bits[g*BSTRIDE + idx] : bit j = x_in[g*64+j][idx]
//   idx 0        -> all ones
//   idx 1..784   -> x[b][idx-1] != 0
//   idx 785..1568-> !(x[b][idx-785] != 0)
// grid (16 groups, 7 f-chunks), block 64 (one wave). Each lane owns one batch
// row; __ballot across the wave assembles the 64-bit column word.
// ---------------------------------------------------------------------------
__global__ __launch_bounds__(64) void pack_bits(const float* __restrict__ x,
                                                u64* __restrict__ bits) {
    const int g    = blockIdx.x;
    const int fb   = blockIdx.y;
    const int lane = threadIdx.x;
    const float4* xrow = (const float4*)(x + (size_t)(g * 64 + lane) * FEAT);
    u64* bg = bits + (size_t)g * BSTRIDE;

    for (int i = 0; i < 28; ++i) {          // 7 chunks * 28 * 4 = 784 features
        const int f4 = fb * 28 + i;
        const float4 v = xrow[f4];
        const int f = f4 * 4;
        const u64 m0 = __ballot(v.x != 0.0f);
        const u64 m1 = __ballot(v.y != 0.0f);
        const u64 m2 = __ballot(v.z != 0.0f);
        const u64 m3 = __ballot(v.w != 0.0f);
        if (lane == 0) {
            bg[1 + f + 0] = m0;  bg[785 + f + 0] = ~m0;
            bg[1 + f + 1] = m1;  bg[785 + f + 1] = ~m1;
            bg[1 + f + 2] = m2;  bg[785 + f + 2] = ~m2;
            bg[1 + f + 3] = m3;  bg[785 + f + 3] = ~m3;
        }
    }
    if (fb == 0 && lane == 0) bg[0] = ~0ull;
}

// ---------------------------------------------------------------------------
// Kernel 2: evaluate the OR-of-ANDs on bit-packed columns.
// grid (16 groups, 16 output-chunks), block 256 = 64 outputs x 4-way OR split.
// Each thread: 8 OR-terms x 16 AND-indices = 128 ds_read_b64 gathers.
// Output dtype is INT32 (reference returns bool -> harness reads np.int32).
// ---------------------------------------------------------------------------
__global__ __launch_bounds__(256) void eval_logic(const int* __restrict__ w,
                                                  const u64* __restrict__ bits,
                                                  int* __restrict__ out) {
    __shared__ u64 lbits[BSTRIDE];
    __shared__ u64 red[256];

    const int g   = blockIdx.x;
    const int ob  = blockIdx.y;
    const int tid = threadIdx.x;

    // Stage this group's bit column (12.8 KB), coalesced.
    const u64* bg = bits + (size_t)g * BSTRIDE;
    for (int i = tid; i < BSTRIDE; i += 256) lbits[i] = bg[i];
    __syncthreads();

    const int o_local = tid & 63;
    const int quad    = tid >> 6;            // which 8 OR-terms this thread does
    const int o       = ob * 64 + o_local;

    // weights[o][t][k], this thread's 8 terms start at t = quad*8
    const int4* wq = (const int4*)(w + ((size_t)o * OR_T + quad * 8) * AND_T);

    u64 orv = 0;
    for (int t = 0; t < 8; ++t) {
        u64 a = ~0ull;
        int zor = 0;                          // OR of the 16 indices
        #pragma unroll
        for (int k = 0; k < 4; ++k) {
            const int4 wi = wq[t * 4 + k];
            zor |= wi.x | wi.y | wi.z | wi.w;
            a &= lbits[wi.x];
            a &= lbits[wi.y];
            a &= lbits[wi.z];
            a &= lbits[wi.w];
        }
        if (zor != 0) orv |= a;               // or_mask: drop all-zero terms
    }

    red[tid] = orv;
    __syncthreads();
    const u64 full = red[o_local] | red[o_local + 64] |
                     red[o_local + 128] | red[o_local + 192];

    // Each quad writes 16 batch rows; lanes across o_local are coalesced.
    int* outg = out + (size_t)(g * 64) * OUTF + (size_t)ob * 64;
    #pragma unroll
    for (int jj = 0; jj < 16; ++jj) {
        const int j = quad * 16 + jj;
        outg[(size_t)j * OUTF + o_local] = (int)((full >> j) & 1);
    }
}

// ---------------------------------------------------------------------------
// Fallback: fused single kernel (no workspace) — packs bits in-block, then
// runs the same evaluation. Used only if ws_size is too small.
// ---------------------------------------------------------------------------
__global__ __launch_bounds__(256) void eval_fused(const float* __restrict__ x,
                                                  const int* __restrict__ w,
                                                  int* __restrict__ out) {
    __shared__ u64 lbits[BSTRIDE];
    __shared__ u64 red[256];

    const int g   = blockIdx.x;
    const int ob  = blockIdx.y;
    const int tid = threadIdx.x;
    const int lane = tid & 63;
    const int wv   = tid >> 6;

    // Pack phase: each wave covers 196 features (49 float4 per lane).
    const float4* xrow = (const float4*)(x + (size_t)(g * 64 + lane) * FEAT);
    for (int i = 0; i < 49; ++i) {
        const int f4 = wv * 49 + i;
        const float4 v = xrow[f4];
        const int f = f4 * 4;
        const u64 m0 = __ballot(v.x != 0.0f);
        const u64 m1 = __ballot(v.y != 0.0f);
        const u64 m2 = __ballot(v.z != 0.0f);
        const u64 m3 = __ballot(v.w != 0.0f);
        if (lane == 0) {
            lbits[1 + f + 0] = m0;  lbits[785 + f + 0] = ~m0;
            lbits[1 + f + 1] = m1;  lbits[785 + f + 1] = ~m1;
            lbits[1 + f + 2] = m2;  lbits[785 + f + 2] = ~m2;
            lbits[1 + f + 3] = m3;  lbits[785 + f + 3] = ~m3;
        }
    }
    if (tid == 0) lbits[0] = ~0ull;
    __syncthreads();

    const int o_local = tid & 63;
    const int quad    = tid >> 6;
    const int o       = ob * 64 + o_local;
    const int4* wq = (const int4*)(w + ((size_t)o * OR_T + quad * 8) * AND_T);

    u64 orv = 0;
    for (int t = 0; t < 8; ++t) {
        u64 a = ~0ull;
        int zor = 0;
        #pragma unroll
        for (int k = 0; k < 4; ++k) {
            const int4 wi = wq[t * 4 + k];
            zor |= wi.x | wi.y | wi.z | wi.w;
            a &= lbits[wi.x];
            a &= lbits[wi.y];
            a &= lbits[wi.z];
            a &= lbits[wi.w];
        }
        if (zor != 0) orv |= a;
    }

    red[tid] = orv;
    __syncthreads();
    const u64 full = red[o_local] | red[o_local + 64] |
                     red[o_local + 128] | red[o_local + 192];

    int* outg = out + (size_t)(g * 64) * OUTF + (size_t)ob * 64;
    #pragma unroll
    for (int jj = 0; jj < 16; ++jj) {
        const int j = quad * 16 + jj;
        outg[(size_t)j * OUTF + o_local] = (int)((full >> j) & 1);
    }
}

extern "C" void kernel_launch(void* const* d_in, const int* in_sizes, int n_in,
                              void* d_out, int out_size, void* d_ws, size_t ws_size,
                              hipStream_t stream) {
    const float* x = (const float*)d_in[0];   // (1024, 784) float32 of 0/1
    const int*   w = (const int*)d_in[1];     // (1024, 32, 16) int32 in [0,1569)
    int* out = (int*)d_out;                   // (1024, 1024) bool -> int32

    const size_t need = (size_t)NGROUP * BSTRIDE * sizeof(u64);   // 204,800 B
    if (ws_size >= need) {
        u64* bits = (u64*)d_ws;
        pack_bits<<<dim3(NGROUP, 7), 64, 0, stream>>>(x, bits);
        eval_logic<<<dim3(NGROUP, OUTF / 64), 256, 0, stream>>>(w, bits, out);
    } else {
        eval_fused<<<dim3(NGROUP, OUTF / 64), 256, 0, stream>>>(x, w, out);
    }
}